// Round 6
// baseline (248.142 us; speedup 1.0000x reference)
//
#include <hip/hip_runtime.h>

typedef __bf16 bf16;
typedef __attribute__((ext_vector_type(8))) __bf16 bf16x8;
typedef __attribute__((ext_vector_type(4))) float floatx4;

#define TOK 2048
#define DD  1024
#define NE  8
#define SMAX 24   // worklist slots (BM=256): <=15 routed + 8 shared, padded to %8==0

#define MFMA16(A,B,C) __builtin_amdgcn_mfma_f32_16x16x32_bf16(A,B,C,0,0,0)

__device__ __forceinline__ void load_lds16(const bf16* g, bf16* l) {
  __builtin_amdgcn_global_load_lds(
      (const __attribute__((address_space(1))) void*)g,
      (__attribute__((address_space(3))) void*)l, 16, 0, 0);
}

// fine-grained barrier: wait only the OLDEST outstanding loads, keep N in flight
#define WBAR(N) asm volatile("s_waitcnt vmcnt(" #N ")\n\ts_barrier" ::: "memory")
#define BARO    asm volatile("s_barrier" ::: "memory")

// ---------------- prep: gate + x->bf16 + weight fp32->bf16 convert + o zero-init ----------------
// One kernel: gate blocks [0,2048), convert blocks [2048, 2048+NCVT), zero blocks after.
// The ~8us serial gate and the o-init hide under the memory-bound convert (~44us).
#define NCVT (8*2046 + 2046 + 8*1023 + 1023)
#define GATEB TOK
#define ZEROB TOK
__global__ __launch_bounds__(256) void prep_kernel(
    const float* __restrict__ x, const float* __restrict__ gate_w,
    const float* __restrict__ gate_b,
    const float* __restrict__ W1, const float* __restrict__ W3,
    const float* __restrict__ W2, const float* __restrict__ Ws1,
    const float* __restrict__ Ws3, const float* __restrict__ Ws2,
    bf16* __restrict__ x_bf, int* __restrict__ eidx, float* __restrict__ ewgt,
    float* __restrict__ ss,
    bf16* __restrict__ w13, bf16* __restrict__ ws13,
    bf16* __restrict__ w2b, bf16* __restrict__ ws2b,
    float* __restrict__ o_r, float* __restrict__ o_s)
{
  const int bid = blockIdx.x, tid = threadIdx.x;

  if (bid >= GATEB) {
    if (bid >= GATEB + NCVT) {
      // ---- zero o_r / o_s row (needed for mlp2's atomic split-K accumulate) ----
      const int t = bid - (GATEB + NCVT);
      const float4 z = {0.f, 0.f, 0.f, 0.f};
      ((float4*)(o_r + (size_t)t * 1024))[tid] = z;
      ((float4*)(o_s + (size_t)t * 1024))[tid] = z;
      return;
    }
    // ---- weight convert (W1/W3 row-interleaved), 4 floats/thread ----
    const int r = bid - GATEB;
    const float* src; bf16* dst;
    if (r < 8 * 2046) {
      const int e = r / 2046, q = r % 2046;
      src = ((q & 1) ? W3 : W1) + ((size_t)e * 1023 + (q >> 1)) * 1024;
      dst = w13 + (size_t)r * 1024;
    } else if (r < 8 * 2046 + 2046) {
      const int q = r - 8 * 2046;
      src = ((q & 1) ? Ws3 : Ws1) + (size_t)(q >> 1) * 1024;
      dst = ws13 + (size_t)q * 1024;
    } else if (r < 8 * 2046 + 2046 + 8 * 1023) {
      const int q = r - (8 * 2046 + 2046);
      src = W2 + (size_t)q * 1024;
      dst = w2b + (size_t)q * 1024;
    } else {
      const int q = r - (8 * 2046 + 2046 + 8 * 1023);
      src = Ws2 + (size_t)q * 1024;
      dst = ws2b + (size_t)q * 1024;
    }
    const float4 f = ((const float4*)src)[tid];
    union { bf16 h[4]; uint2 u; } p;
    p.h[0] = (bf16)f.x; p.h[1] = (bf16)f.y; p.h[2] = (bf16)f.z; p.h[3] = (bf16)f.w;
    ((uint2*)dst)[tid] = p.u;
    return;
  }

  // ---- gate + x->bf16 + ss zero (ss_r, ss_z) ----
  const int t = bid;
  if (tid < 2) ss[tid * TOK + t] = 0.f;
  const float4 v = ((const float4*)(x + (size_t)t * DD))[tid];
  union { bf16 h[4]; uint2 u; } pk;
  pk.h[0] = (bf16)v.x; pk.h[1] = (bf16)v.y; pk.h[2] = (bf16)v.z; pk.h[3] = (bf16)v.w;
  ((uint2*)(x_bf + (size_t)t * DD))[tid] = pk.u;

  float acc[NE];
#pragma unroll
  for (int e = 0; e < NE; ++e) acc[e] = 0.f;
  const float vv[4] = {v.x, v.y, v.z, v.w};
#pragma unroll
  for (int i = 0; i < 4; ++i) {
    const int d = tid * 4 + i;
    if (d >= 1) {
#pragma unroll
      for (int e = 0; e < NE; ++e) acc[e] += vv[i] * gate_w[e * (DD - 1) + d - 1];
    }
  }
#pragma unroll
  for (int off = 32; off > 0; off >>= 1) {
#pragma unroll
    for (int e = 0; e < NE; ++e) acc[e] += __shfl_down(acc[e], off);
  }
  __shared__ float red[4][NE];
  const int wid = tid >> 6, lane = tid & 63;
  if (lane == 0) {
#pragma unroll
    for (int e = 0; e < NE; ++e) red[wid][e] = acc[e];
  }
  __syncthreads();
  if (tid == 0) {
    float lg[NE];
#pragma unroll
    for (int e = 0; e < NE; ++e) lg[e] = red[0][e] + red[1][e] + red[2][e] + red[3][e];
    float m = lg[0];
    for (int e = 1; e < NE; ++e) m = fmaxf(m, lg[e]);
    float ex[NE], s = 0.f;
    for (int e = 0; e < NE; ++e) { ex[e] = expf(lg[e] - m); s += ex[e]; }
    const float inv = 1.f / s;
    int best = 0; float bb = ex[0] * inv + gate_b[0];
    for (int e = 1; e < NE; ++e) {
      const float b = ex[e] * inv + gate_b[e];
      if (b > bb) { bb = b; best = e; }
    }
    eidx[t] = best;
    ewgt[t] = ex[best] * inv;
  }
}

// ---------------- routing: count + prefix + scatter + single BM=256 worklist ----------------
__global__ __launch_bounds__(256) void route_kernel(
    const int* __restrict__ eidx, int* __restrict__ perm,
    int* __restrict__ pos_of, int4* __restrict__ wl, int* __restrict__ n1)
{
  __shared__ int cnt[NE], off[NE], bas[NE + 1];
  const int tid = threadIdx.x;
  if (tid < NE) cnt[tid] = 0;
  __syncthreads();
  for (int t = tid; t < TOK; t += 256) atomicAdd(&cnt[eidx[t]], 1);
  __syncthreads();
  if (tid == 0) {
    int run = 0;
    for (int e = 0; e < NE; ++e) { bas[e] = run; off[e] = run; run += cnt[e]; }
    bas[NE] = run;
    int n = 0;
    for (int e = 0; e < NE; ++e)
      for (int r0 = 0; r0 < cnt[e]; r0 += 256) {
        int rows = cnt[e] - r0; if (rows > 256) rows = 256;
        wl[n++] = make_int4(bas[e] + r0, rows, e, 0);
      }
    for (int r0 = 0; r0 < TOK; r0 += 256) wl[n++] = make_int4(r0, 256, NE, 0);
    *n1 = n;
  }
  __syncthreads();
  for (int t = tid; t < TOK; t += 256) {
    const int e = eidx[t];
    const int p = atomicAdd(&off[e], 1);
    perm[p] = t;
    pos_of[t] = p;
  }
}

// ---------------- mlp1: BM=256 x BN=256 x BK=64, 16 waves, dbuf + vmcnt(4) ----------------
// UNCHANGED from round 4 (measured 44us, 0 conflicts, best per-CU staging rate).
__global__ __launch_bounds__(1024) void mlp1_kernel(
    const bf16* __restrict__ x_bf, const bf16* __restrict__ w13,
    const bf16* __restrict__ ws13,
    const int* __restrict__ perm, const int4* __restrict__ wl,
    const int* __restrict__ wl_n,
    bf16* __restrict__ h_r, bf16* __restrict__ h_s,
    float* __restrict__ ss_r, float* __restrict__ ss_z)
{
  const int bid = blockIdx.x;
  const int slot = bid % SMAX, nt = bid / SMAX;   // nt in 0..7
  if (slot >= *wl_n) return;
  const int4 wle = wl[slot];
  const int mbase = wle.x, rows = wle.y, eid = wle.z;
  const int tid = threadIdx.x;
  const bool routed = (eid < NE);
  const bf16* bmat = routed ? w13 + (size_t)eid * 2046 * 1024 : ws13;
  bf16* hbuf  = routed ? h_r : h_s;
  float* ssbuf = routed ? ss_r : ss_z;

  extern __shared__ __align__(16) bf16 smem[];
  bf16* const Asb[2] = {smem, smem + 16384};            // 256x64 each
  bf16* const Bsb[2] = {smem + 32768, smem + 49152};    // 256x64 each
  __shared__ int toks[256];
  if (tid < 256) {
    int r = tid < rows ? tid : rows - 1;
    toks[tid] = routed ? perm[mbase + r] : (mbase + r);
  }
  __syncthreads();

  const int wid = tid >> 6, lane = tid & 63;
  const int srow = lane >> 3;
  const int kbg  = (lane & 7) ^ (srow & 7);
  const bf16 *aG0, *aG1, *bG0, *bG1;
  int aL0o, aL1o, bL0o, bL1o;
  {
    const int r0 = wid * 16;
    aG0 = x_bf + (size_t)toks[r0 + 0 + srow] * 1024 + kbg * 8;
    aG1 = x_bf + (size_t)toks[r0 + 8 + srow] * 1024 + kbg * 8;
    aL0o = (r0 + 0) * 64; aL1o = (r0 + 8) * 64;
    int b0 = nt * 256 + r0 + 0 + srow; if (b0 > 2045) b0 = 2045;
    int b1 = nt * 256 + r0 + 8 + srow; if (b1 > 2045) b1 = 2045;
    bG0 = bmat + (size_t)b0 * 1024 + kbg * 8;
    bG1 = bmat + (size_t)b1 * 1024 + kbg * 8;
    bL0o = (r0 + 0) * 64; bL1o = (r0 + 8) * 64;
  }

  const int lrow = lane & 15, quad = lane >> 4, sw = lane & 7;
  const int wrow = (wid >> 2) * 64, wcol = (wid & 3) * 64;
  int aoff[4], boff[4], koff[2];
#pragma unroll
  for (int mi = 0; mi < 4; ++mi) aoff[mi] = (wrow + mi * 16 + lrow) * 64;
#pragma unroll
  for (int ni = 0; ni < 4; ++ni) boff[ni] = (wcol + ni * 16 + lrow) * 64;
#pragma unroll
  for (int kk = 0; kk < 2; ++kk) koff[kk] = ((kk * 4 + quad) ^ sw) * 8;

  const floatx4 fz = {0.f, 0.f, 0.f, 0.f};
  floatx4 acc[4][4];
#pragma unroll
  for (int mi = 0; mi < 4; ++mi)
#pragma unroll
    for (int ni = 0; ni < 4; ++ni) acc[mi][ni] = fz;

#define STAGE1(KE, BUF) { \
    load_lds16(aG0 + (KE), Asb[BUF] + aL0o); load_lds16(aG1 + (KE), Asb[BUF] + aL1o); \
    load_lds16(bG0 + (KE), Bsb[BUF] + bL0o); load_lds16(bG1 + (KE), Bsb[BUF] + bL1o); }

#define COMP1(BUF) { \
_Pragma("unroll") \
    for (int kk = 0; kk < 2; ++kk) { \
      bf16x8 av[4], bv[4]; \
_Pragma("unroll") \
      for (int mi = 0; mi < 4; ++mi) av[mi] = *(const bf16x8*)(Asb[BUF] + aoff[mi] + koff[kk]); \
_Pragma("unroll") \
      for (int ni = 0; ni < 4; ++ni) bv[ni] = *(const bf16x8*)(Bsb[BUF] + boff[ni] + koff[kk]); \
_Pragma("unroll") \
      for (int mi = 0; mi < 4; ++mi) \
_Pragma("unroll") \
        for (int ni = 0; ni < 4; ++ni) \
          acc[mi][ni] = MFMA16(av[mi], bv[ni], acc[mi][ni]); \
    } }

  STAGE1(0, 0)
  STAGE1(64, 1)
#pragma unroll 1
  for (int t = 0; t < 7; ++t) {
    const int ke = t * 128;
    WBAR(4); COMP1(0) BARO; STAGE1(ke + 128, 0)
    WBAR(4); COMP1(1) BARO; STAGE1(ke + 192, 1)
  }
  WBAR(4); COMP1(0)
  WBAR(0); COMP1(1)
#undef STAGE1
#undef COMP1

  // epilogue: interleaved cols -> (s1,s3) via lane^1 shuffle, gate, store h(bf16), sumsq
#pragma unroll
  for (int mi = 0; mi < 4; ++mi) {
#pragma unroll
    for (int r = 0; r < 4; ++r) {
      const int row = wrow + mi * 16 + quad * 4 + r;
      const bool rowok = row < rows;
      float ssum = 0.f;
#pragma unroll
      for (int ni = 0; ni < 4; ++ni) {
        const float c = acc[mi][ni][r];
        const float partner = __shfl_xor(c, 1);
        const float s1 = (lane & 1) ? partner : c;
        const float s3 = (lane & 1) ? c : partner;
        const float sp = (s1 / (1.f + __expf(-s1))) * s3;
        const int P = (nt * 256 + wcol + ni * 16 + lrow) >> 1;
        const bool ok = rowok && ((lane & 1) == 0) && (P < 1023);
        if (ok) hbuf[(size_t)(mbase + row) * 1024 + 1 + P] = (bf16)sp;
        ssum += ok ? sp * sp : 0.f;
      }
      ssum += __shfl_xor(ssum, 1);
      ssum += __shfl_xor(ssum, 2);
      ssum += __shfl_xor(ssum, 4);
      ssum += __shfl_xor(ssum, 8);
      if (lrow == 0 && rowok) atomicAdd(ssbuf + mbase + row, ssum);
    }
  }
}

// ---------------- h[:,0] = sqrt(sumsq + 1) ----------------
__global__ __launch_bounds__(256) void finalize_t_kernel(
    const float* __restrict__ ss_r, const float* __restrict__ ss_z,
    bf16* __restrict__ h_r, bf16* __restrict__ h_s)
{
  const int i = blockIdx.x * 256 + threadIdx.x;
  if (i < TOK) {
    h_r[(size_t)i * 1024] = (bf16)sqrtf(ss_r[i] + 1.0f);
    h_s[(size_t)i * 1024] = (bf16)sqrtf(ss_z[i] + 1.0f);
  }
}

// ---------------- mlp2: BM=256 x BN=256, SPLIT-K x2 (8 steps of BK=64 each) ----------------
// Exact clone of mlp1's staging shape (16 waves, 4 instrs/wave, WBAR(4), 128KB LDS) that
// uniquely measured ~9.5 B/cy/CU — only K-range and epilogue differ. 17 slots x 4 nt x
// 2 kh = 136 blocks (was 68): halves staged bytes/CU AND doubles active CUs.
// Epilogue: plain fp32 atomicAdd into zero-initialized o (commutative; no ss here —
// combine computes the sumsqs from the rows it already reads).
__global__ __launch_bounds__(1024) void mlp2_kernel(
    const bf16* __restrict__ h_r, const bf16* __restrict__ h_s,
    const bf16* __restrict__ w2b, const bf16* __restrict__ ws2b,
    const int4* __restrict__ wl, const int* __restrict__ wl_n,
    float* __restrict__ o_r, float* __restrict__ o_s)
{
  const int bid = blockIdx.x;
  const int slot = bid % SMAX;
  const int rest = bid / SMAX;        // 0..7
  const int nt = rest & 3, kh = rest >> 2;
  if (slot >= *wl_n) return;
  const int4 wle = wl[slot];
  const int mbase = wle.x, rows = wle.y, eid = wle.z;
  const int tid = threadIdx.x;
  const bool routed = (eid < NE);
  const bf16* abuf = routed ? h_r : h_s;
  const bf16* bmat = routed ? w2b + (size_t)eid * 1023 * 1024 : ws2b;
  float* obuf = routed ? o_r : o_s;
  const int n0 = nt * 256;
  const int kbase = kh * 512;

  extern __shared__ __align__(16) bf16 smem[];
  bf16* const Asb[2] = {smem, smem + 16384};            // 256x64 each
  bf16* const Bsb[2] = {smem + 32768, smem + 49152};    // 256x64 each

  const int wid = tid >> 6, lane = tid & 63;
  const int srow = lane >> 3;
  const int kbg  = (lane & 7) ^ (srow & 7);
  const bf16 *aG0, *aG1, *bG0, *bG1;
  int aL0o, aL1o, bL0o, bL1o;
  {
    const int r0 = wid * 16;
    int ra0 = r0 + 0 + srow; if (ra0 >= rows) ra0 = rows - 1;
    int ra1 = r0 + 8 + srow; if (ra1 >= rows) ra1 = rows - 1;
    aG0 = abuf + (size_t)(mbase + ra0) * 1024 + kbase + kbg * 8;
    aG1 = abuf + (size_t)(mbase + ra1) * 1024 + kbase + kbg * 8;
    aL0o = (r0 + 0) * 64; aL1o = (r0 + 8) * 64;
    int b0 = n0 + r0 + 0 + srow; if (b0 > 1022) b0 = 1022;
    int b1 = n0 + r0 + 8 + srow; if (b1 > 1022) b1 = 1022;
    bG0 = bmat + (size_t)b0 * 1024 + kbase + kbg * 8;
    bG1 = bmat + (size_t)b1 * 1024 + kbase + kbg * 8;
    bL0o = (r0 + 0) * 64; bL1o = (r0 + 8) * 64;
  }

  const int lrow = lane & 15, quad = lane >> 4, sw = lane & 7;
  const int wrow = (wid >> 2) * 64, wcol = (wid & 3) * 64;
  int aoff[4], boff[4], koff[2];
#pragma unroll
  for (int mi = 0; mi < 4; ++mi) aoff[mi] = (wrow + mi * 16 + lrow) * 64;
#pragma unroll
  for (int ni = 0; ni < 4; ++ni) boff[ni] = (wcol + ni * 16 + lrow) * 64;
#pragma unroll
  for (int kk = 0; kk < 2; ++kk) koff[kk] = ((kk * 4 + quad) ^ sw) * 8;

  const floatx4 fz = {0.f, 0.f, 0.f, 0.f};
  floatx4 acc[4][4];
#pragma unroll
  for (int mi = 0; mi < 4; ++mi)
#pragma unroll
    for (int ni = 0; ni < 4; ++ni) acc[mi][ni] = fz;

#define STAGE2(KE, BUF) { \
    load_lds16(aG0 + (KE), Asb[BUF] + aL0o); load_lds16(aG1 + (KE), Asb[BUF] + aL1o); \
    load_lds16(bG0 + (KE), Bsb[BUF] + bL0o); load_lds16(bG1 + (KE), Bsb[BUF] + bL1o); }

#define COMP2(BUF) { \
_Pragma("unroll") \
    for (int kk = 0; kk < 2; ++kk) { \
      bf16x8 av[4], bv[4]; \
_Pragma("unroll") \
      for (int mi = 0; mi < 4; ++mi) av[mi] = *(const bf16x8*)(Asb[BUF] + aoff[mi] + koff[kk]); \
_Pragma("unroll") \
      for (int ni = 0; ni < 4; ++ni) bv[ni] = *(const bf16x8*)(Bsb[BUF] + boff[ni] + koff[kk]); \
_Pragma("unroll") \
      for (int mi = 0; mi < 4; ++mi) \
_Pragma("unroll") \
        for (int ni = 0; ni < 4; ++ni) \
          acc[mi][ni] = MFMA16(av[mi], bv[ni], acc[mi][ni]); \
    } }

  // 8 K-steps (this block's half of K)
  STAGE2(0, 0)
  STAGE2(64, 1)
#pragma unroll 1
  for (int t = 0; t < 3; ++t) {
    const int ke = t * 128;
    WBAR(4); COMP2(0) BARO; STAGE2(ke + 128, 0)
    WBAR(4); COMP2(1) BARO; STAGE2(ke + 192, 1)
  }
  WBAR(4); COMP2(0)
  WBAR(0); COMP2(1)
#undef STAGE2
#undef COMP2

  // epilogue: atomic fp32 accumulate into o (zero-initialized by prep)
#pragma unroll
  for (int mi = 0; mi < 4; ++mi) {
#pragma unroll
    for (int r = 0; r < 4; ++r) {
      const int row = wrow + mi * 16 + quad * 4 + r;
      if (row < rows) {
        float* orow = obuf + (size_t)(mbase + row) * 1024;
#pragma unroll
        for (int ni = 0; ni < 4; ++ni) {
          const int n = n0 + wcol + ni * 16 + lrow;
          if (n < 1023) atomicAdd(orow + n, acc[mi][ni][r]);
        }
      }
    }
  }
}

// ---------------- final LResNet combine + Lorentz normalize (ss computed inline) ----------------
__global__ __launch_bounds__(256) void combine_kernel(
    const float* __restrict__ o_r, const float* __restrict__ o_s,
    const int* __restrict__ pos_of, const float* __restrict__ wgt,
    float* __restrict__ out)
{
  const int t = blockIdx.x, tid = threadIdx.x;
  const int p = pos_of[t];
  const float w = wgt[t];
  const float4 oz = ((const float4*)(o_s + (size_t)t * 1024))[tid];
  const float4 oe = ((const float4*)(o_r + (size_t)p * 1024))[tid];
  const float tw = 2.f * w;
  float c0 = oz.x + tw * oe.x;
  float c1 = oz.y + tw * oe.y;
  float c2 = oz.z + tw * oe.z;
  float c3 = (tid == 255) ? 0.f : (oz.w + tw * oe.w);  // n=1023 is padding
  float sc = c0 * c0 + c1 * c1 + c2 * c2 + c3 * c3;
  float sz = oz.x * oz.x + oz.y * oz.y + oz.z * oz.z + ((tid == 255) ? 0.f : oz.w * oz.w);
  float sr = oe.x * oe.x + oe.y * oe.y + oe.z * oe.z + ((tid == 255) ? 0.f : oe.w * oe.w);
#pragma unroll
  for (int off = 32; off > 0; off >>= 1) {
    sc += __shfl_down(sc, off);
    sz += __shfl_down(sz, off);
    sr += __shfl_down(sr, off);
  }
  __shared__ float rs[3][4];
  if ((tid & 63) == 0) {
    rs[0][tid >> 6] = sc; rs[1][tid >> 6] = sz; rs[2][tid >> 6] = sr;
  }
  __syncthreads();
  const float space2 = rs[0][0] + rs[0][1] + rs[0][2] + rs[0][3];
  const float ss_oz  = rs[1][0] + rs[1][1] + rs[1][2] + rs[1][3];
  const float ss_or  = rs[2][0] + rs[2][1] + rs[2][2] + rs[2][3];
  const float comb0 = sqrtf(ss_oz + 1.f) + 2.f + 2.f * w * sqrtf(ss_or + 1.f);
  const float li = space2 - comb0 * comb0;
  const float inv = 1.f / sqrtf(fmaxf(fabsf(li), 1e-8f));
  float* orow = out + (size_t)t * 1024;
  const int j = 1 + tid * 4;
  orow[j]     = c0 * inv;
  orow[j + 1] = c1 * inv;
  orow[j + 2] = c2 * inv;
  if (tid != 255) orow[j + 3] = c3 * inv;
  if (tid == 0) orow[0] = comb0 * inv;
}

extern "C" void kernel_launch(void* const* d_in, const int* in_sizes, int n_in,
                              void* d_out, int out_size, void* d_ws, size_t ws_size,
                              hipStream_t stream) {
  const float* x      = (const float*)d_in[0];
  const float* gate_w = (const float*)d_in[1];
  const float* gate_b = (const float*)d_in[2];
  const float* W1     = (const float*)d_in[3];
  const float* W3     = (const float*)d_in[4];
  const float* W2     = (const float*)d_in[5];
  const float* Ws1    = (const float*)d_in[6];
  const float* Ws3    = (const float*)d_in[7];
  const float* Ws2    = (const float*)d_in[8];
  float* out = (float*)d_out;

  char* ws = (char*)d_ws;
  size_t off = 0;
  auto alloc = [&](size_t bytes) {
    void* p = ws + off;
    off += (bytes + 255) & ~(size_t)255;
    return p;
  };
  bf16*  x_bf = (bf16*) alloc((size_t)TOK * 1024 * 2);
  bf16*  h_r  = (bf16*) alloc((size_t)TOK * 1024 * 2);
  bf16*  h_s  = (bf16*) alloc((size_t)TOK * 1024 * 2);
  float* o_r  = (float*)alloc((size_t)TOK * 1024 * 4);
  float* o_s  = (float*)alloc((size_t)TOK * 1024 * 4);
  float* ss   = (float*)alloc((size_t)2 * TOK * 4);
  int*   eidx = (int*)  alloc((size_t)TOK * 4);
  float* ewgt = (float*)alloc((size_t)TOK * 4);
  int*   perm = (int*)  alloc((size_t)TOK * 4);
  int*   posf = (int*)  alloc((size_t)TOK * 4);
  int4*  wl1  = (int4*) alloc((size_t)SMAX * 16);
  int*   wn   = (int*)  alloc(32);
  bf16*  w13  = (bf16*) alloc((size_t)8 * 2046 * 1024 * 2);
  bf16*  ws13 = (bf16*) alloc((size_t)2046 * 1024 * 2);
  bf16*  w2b  = (bf16*) alloc((size_t)8 * 1023 * 1024 * 2);
  bf16*  ws2b = (bf16*) alloc((size_t)1023 * 1024 * 2);

  float* ss_r  = ss;
  float* ss_z  = ss + TOK;

  // both MLP kernels use 128KB dynamic LDS (dbuf 256x64 A + 256x64 B)
  const int MLP_LDS = 2 * (256 * 64 + 256 * 64) * 2;  // 131072 B
  (void)hipFuncSetAttribute((const void*)mlp1_kernel,
                            hipFuncAttributeMaxDynamicSharedMemorySize, MLP_LDS);
  (void)hipFuncSetAttribute((const void*)mlp2_kernel,
                            hipFuncAttributeMaxDynamicSharedMemorySize, MLP_LDS);

  prep_kernel<<<GATEB + NCVT + ZEROB, 256, 0, stream>>>(
      x, gate_w, gate_b, W1, W3, W2, Ws1, Ws3, Ws2,
      x_bf, eidx, ewgt, ss, w13, ws13, w2b, ws2b, o_r, o_s);
  route_kernel<<<1, 256, 0, stream>>>(eidx, perm, posf, wl1, wn);
  mlp1_kernel<<<8 * SMAX, 1024, MLP_LDS, stream>>>(x_bf, w13, ws13, perm, wl1, wn,
                                                   h_r, h_s, ss_r, ss_z);
  finalize_t_kernel<<<8, 256, 0, stream>>>(ss_r, ss_z, h_r, h_s);
  mlp2_kernel<<<8 * SMAX, 1024, MLP_LDS, stream>>>(h_r, h_s, w2b, ws2b, wl1, wn,
                                                   o_r, o_s);
  combine_kernel<<<TOK, 256, 0, stream>>>(o_r, o_s, posf, ewgt, out);
}

// Round 7
// 231.564 us; speedup vs baseline: 1.0716x; 1.0716x over previous
//
#include <hip/hip_runtime.h>

typedef __bf16 bf16;
typedef __attribute__((ext_vector_type(8))) __bf16 bf16x8;
typedef __attribute__((ext_vector_type(4))) float floatx4;

#define TOK 2048
#define DD  1024
#define NE  8
#define SMAX 24   // worklist slots (BM=256): <=15 routed + 8 shared, padded to %8==0

#define MFMA16(A,B,C) __builtin_amdgcn_mfma_f32_16x16x32_bf16(A,B,C,0,0,0)

__device__ __forceinline__ void load_lds16(const bf16* g, bf16* l) {
  __builtin_amdgcn_global_load_lds(
      (const __attribute__((address_space(1))) void*)g,
      (__attribute__((address_space(3))) void*)l, 16, 0, 0);
}

// fine-grained barrier: wait only the OLDEST outstanding loads, keep N in flight
#define WBAR(N) asm volatile("s_waitcnt vmcnt(" #N ")\n\ts_barrier" ::: "memory")
#define BARO    asm volatile("s_barrier" ::: "memory")

// ---------------- prep: gate + x->bf16 + weight fp32->bf16 convert + w2col0 extract ----------------
// Gate blocks [0,2048): gate + x->bf16 + ss zero + h[:,0]=0.
// Convert blocks [2048, 2048+NCVT): fp32->bf16; W2 rows also drop their col-0 element
// into a compact fp32 table (w2c0) so mlp2 can skip the time column entirely
// (o = t*W2[:,0] + sp@W2[:,1:]^T; combine adds the rank-1 term in fp32).
#define NCVT (8*2046 + 2046 + 8*1023 + 1023)
#define GATEB TOK
__global__ __launch_bounds__(256) void prep_kernel(
    const float* __restrict__ x, const float* __restrict__ gate_w,
    const float* __restrict__ gate_b,
    const float* __restrict__ W1, const float* __restrict__ W3,
    const float* __restrict__ W2, const float* __restrict__ Ws1,
    const float* __restrict__ Ws3, const float* __restrict__ Ws2,
    bf16* __restrict__ x_bf, int* __restrict__ eidx, float* __restrict__ ewgt,
    float* __restrict__ ss,
    bf16* __restrict__ w13, bf16* __restrict__ ws13,
    bf16* __restrict__ w2b, bf16* __restrict__ ws2b,
    float* __restrict__ w2c0_r, float* __restrict__ w2c0_s,
    bf16* __restrict__ h_r, bf16* __restrict__ h_s)
{
  const int bid = blockIdx.x, tid = threadIdx.x;

  if (bid >= GATEB) {
    // ---- weight convert (W1/W3 row-interleaved), 4 floats/thread ----
    const int r = bid - GATEB;
    const float* src; bf16* dst;
    float* c0dst = nullptr;
    if (r < 8 * 2046) {
      const int e = r / 2046, q = r % 2046;
      src = ((q & 1) ? W3 : W1) + ((size_t)e * 1023 + (q >> 1)) * 1024;
      dst = w13 + (size_t)r * 1024;
    } else if (r < 8 * 2046 + 2046) {
      const int q = r - 8 * 2046;
      src = ((q & 1) ? Ws3 : Ws1) + (size_t)(q >> 1) * 1024;
      dst = ws13 + (size_t)q * 1024;
    } else if (r < 8 * 2046 + 2046 + 8 * 1023) {
      const int q = r - (8 * 2046 + 2046);
      src = W2 + (size_t)q * 1024;
      dst = w2b + (size_t)q * 1024;
      c0dst = w2c0_r + (size_t)(q / 1023) * 1024 + (q % 1023);  // padded [E][1024]
    } else {
      const int q = r - (8 * 2046 + 2046 + 8 * 1023);
      src = Ws2 + (size_t)q * 1024;
      dst = ws2b + (size_t)q * 1024;
      c0dst = w2c0_s + q;
    }
    const float4 f = ((const float4*)src)[tid];
    if (tid == 0 && c0dst) *c0dst = f.x;   // W2[:,0] (time-lift column)
    union { bf16 h[4]; uint2 u; } p;
    p.h[0] = (bf16)f.x; p.h[1] = (bf16)f.y; p.h[2] = (bf16)f.z; p.h[3] = (bf16)f.w;
    ((uint2*)dst)[tid] = p.u;
    return;
  }

  // ---- gate + x->bf16 + ss zero (ss_r, ss_z) + h[:,0]=0 ----
  const int t = bid;
  if (tid < 2) ss[tid * TOK + t] = 0.f;
  if (tid == 2) h_r[(size_t)t * 1024] = (bf16)0.f;
  if (tid == 3) h_s[(size_t)t * 1024] = (bf16)0.f;
  const float4 v = ((const float4*)(x + (size_t)t * DD))[tid];
  union { bf16 h[4]; uint2 u; } pk;
  pk.h[0] = (bf16)v.x; pk.h[1] = (bf16)v.y; pk.h[2] = (bf16)v.z; pk.h[3] = (bf16)v.w;
  ((uint2*)(x_bf + (size_t)t * DD))[tid] = pk.u;

  float acc[NE];
#pragma unroll
  for (int e = 0; e < NE; ++e) acc[e] = 0.f;
  const float vv[4] = {v.x, v.y, v.z, v.w};
#pragma unroll
  for (int i = 0; i < 4; ++i) {
    const int d = tid * 4 + i;
    if (d >= 1) {
#pragma unroll
      for (int e = 0; e < NE; ++e) acc[e] += vv[i] * gate_w[e * (DD - 1) + d - 1];
    }
  }
#pragma unroll
  for (int off = 32; off > 0; off >>= 1) {
#pragma unroll
    for (int e = 0; e < NE; ++e) acc[e] += __shfl_down(acc[e], off);
  }
  __shared__ float red[4][NE];
  const int wid = tid >> 6, lane = tid & 63;
  if (lane == 0) {
#pragma unroll
    for (int e = 0; e < NE; ++e) red[wid][e] = acc[e];
  }
  __syncthreads();
  if (tid == 0) {
    float lg[NE];
#pragma unroll
    for (int e = 0; e < NE; ++e) lg[e] = red[0][e] + red[1][e] + red[2][e] + red[3][e];
    float m = lg[0];
    for (int e = 1; e < NE; ++e) m = fmaxf(m, lg[e]);
    float ex[NE], s = 0.f;
    for (int e = 0; e < NE; ++e) { ex[e] = expf(lg[e] - m); s += ex[e]; }
    const float inv = 1.f / s;
    int best = 0; float bb = ex[0] * inv + gate_b[0];
    for (int e = 1; e < NE; ++e) {
      const float b = ex[e] * inv + gate_b[e];
      if (b > bb) { bb = b; best = e; }
    }
    eidx[t] = best;
    ewgt[t] = ex[best] * inv;
  }
}

// ---------------- routing: count + prefix + scatter + single BM=256 worklist ----------------
__global__ __launch_bounds__(256) void route_kernel(
    const int* __restrict__ eidx, int* __restrict__ perm,
    int* __restrict__ pos_of, int4* __restrict__ wl, int* __restrict__ n1)
{
  __shared__ int cnt[NE], off[NE], bas[NE + 1];
  const int tid = threadIdx.x;
  if (tid < NE) cnt[tid] = 0;
  __syncthreads();
  for (int t = tid; t < TOK; t += 256) atomicAdd(&cnt[eidx[t]], 1);
  __syncthreads();
  if (tid == 0) {
    int run = 0;
    for (int e = 0; e < NE; ++e) { bas[e] = run; off[e] = run; run += cnt[e]; }
    bas[NE] = run;
    int n = 0;
    for (int e = 0; e < NE; ++e)
      for (int r0 = 0; r0 < cnt[e]; r0 += 256) {
        int rows = cnt[e] - r0; if (rows > 256) rows = 256;
        wl[n++] = make_int4(bas[e] + r0, rows, e, 0);
      }
    for (int r0 = 0; r0 < TOK; r0 += 256) wl[n++] = make_int4(r0, 256, NE, 0);
    *n1 = n;
  }
  __syncthreads();
  for (int t = tid; t < TOK; t += 256) {
    const int e = eidx[t];
    const int p = atomicAdd(&off[e], 1);
    perm[p] = t;
    pos_of[t] = p;
  }
}

// ---------------- mlp1: BM=256 x BN=256 x BK=64, 16 waves, dbuf + vmcnt(4) ----------------
// UNCHANGED control (measured 44us, 0 conflicts, best per-CU staging rate).
__global__ __launch_bounds__(1024) void mlp1_kernel(
    const bf16* __restrict__ x_bf, const bf16* __restrict__ w13,
    const bf16* __restrict__ ws13,
    const int* __restrict__ perm, const int4* __restrict__ wl,
    const int* __restrict__ wl_n,
    bf16* __restrict__ h_r, bf16* __restrict__ h_s,
    float* __restrict__ ss_r, float* __restrict__ ss_z)
{
  const int bid = blockIdx.x;
  const int slot = bid % SMAX, nt = bid / SMAX;   // nt in 0..7
  if (slot >= *wl_n) return;
  const int4 wle = wl[slot];
  const int mbase = wle.x, rows = wle.y, eid = wle.z;
  const int tid = threadIdx.x;
  const bool routed = (eid < NE);
  const bf16* bmat = routed ? w13 + (size_t)eid * 2046 * 1024 : ws13;
  bf16* hbuf  = routed ? h_r : h_s;
  float* ssbuf = routed ? ss_r : ss_z;

  extern __shared__ __align__(16) bf16 smem[];
  bf16* const Asb[2] = {smem, smem + 16384};            // 256x64 each
  bf16* const Bsb[2] = {smem + 32768, smem + 49152};    // 256x64 each
  __shared__ int toks[256];
  if (tid < 256) {
    int r = tid < rows ? tid : rows - 1;
    toks[tid] = routed ? perm[mbase + r] : (mbase + r);
  }
  __syncthreads();

  const int wid = tid >> 6, lane = tid & 63;
  const int srow = lane >> 3;
  const int kbg  = (lane & 7) ^ (srow & 7);
  const bf16 *aG0, *aG1, *bG0, *bG1;
  int aL0o, aL1o, bL0o, bL1o;
  {
    const int r0 = wid * 16;
    aG0 = x_bf + (size_t)toks[r0 + 0 + srow] * 1024 + kbg * 8;
    aG1 = x_bf + (size_t)toks[r0 + 8 + srow] * 1024 + kbg * 8;
    aL0o = (r0 + 0) * 64; aL1o = (r0 + 8) * 64;
    int b0 = nt * 256 + r0 + 0 + srow; if (b0 > 2045) b0 = 2045;
    int b1 = nt * 256 + r0 + 8 + srow; if (b1 > 2045) b1 = 2045;
    bG0 = bmat + (size_t)b0 * 1024 + kbg * 8;
    bG1 = bmat + (size_t)b1 * 1024 + kbg * 8;
    bL0o = (r0 + 0) * 64; bL1o = (r0 + 8) * 64;
  }

  const int lrow = lane & 15, quad = lane >> 4, sw = lane & 7;
  const int wrow = (wid >> 2) * 64, wcol = (wid & 3) * 64;
  int aoff[4], boff[4], koff[2];
#pragma unroll
  for (int mi = 0; mi < 4; ++mi) aoff[mi] = (wrow + mi * 16 + lrow) * 64;
#pragma unroll
  for (int ni = 0; ni < 4; ++ni) boff[ni] = (wcol + ni * 16 + lrow) * 64;
#pragma unroll
  for (int kk = 0; kk < 2; ++kk) koff[kk] = ((kk * 4 + quad) ^ sw) * 8;

  const floatx4 fz = {0.f, 0.f, 0.f, 0.f};
  floatx4 acc[4][4];
#pragma unroll
  for (int mi = 0; mi < 4; ++mi)
#pragma unroll
    for (int ni = 0; ni < 4; ++ni) acc[mi][ni] = fz;

#define STAGE1(KE, BUF) { \
    load_lds16(aG0 + (KE), Asb[BUF] + aL0o); load_lds16(aG1 + (KE), Asb[BUF] + aL1o); \
    load_lds16(bG0 + (KE), Bsb[BUF] + bL0o); load_lds16(bG1 + (KE), Bsb[BUF] + bL1o); }

#define COMP1(BUF) { \
_Pragma("unroll") \
    for (int kk = 0; kk < 2; ++kk) { \
      bf16x8 av[4], bv[4]; \
_Pragma("unroll") \
      for (int mi = 0; mi < 4; ++mi) av[mi] = *(const bf16x8*)(Asb[BUF] + aoff[mi] + koff[kk]); \
_Pragma("unroll") \
      for (int ni = 0; ni < 4; ++ni) bv[ni] = *(const bf16x8*)(Bsb[BUF] + boff[ni] + koff[kk]); \
_Pragma("unroll") \
      for (int mi = 0; mi < 4; ++mi) \
_Pragma("unroll") \
        for (int ni = 0; ni < 4; ++ni) \
          acc[mi][ni] = MFMA16(av[mi], bv[ni], acc[mi][ni]); \
    } }

  STAGE1(0, 0)
  STAGE1(64, 1)
#pragma unroll 1
  for (int t = 0; t < 7; ++t) {
    const int ke = t * 128;
    WBAR(4); COMP1(0) BARO; STAGE1(ke + 128, 0)
    WBAR(4); COMP1(1) BARO; STAGE1(ke + 192, 1)
  }
  WBAR(4); COMP1(0)
  WBAR(0); COMP1(1)
#undef STAGE1
#undef COMP1

  // epilogue: interleaved cols -> (s1,s3) via lane^1 shuffle, gate, store h(bf16), sumsq
#pragma unroll
  for (int mi = 0; mi < 4; ++mi) {
#pragma unroll
    for (int r = 0; r < 4; ++r) {
      const int row = wrow + mi * 16 + quad * 4 + r;
      const bool rowok = row < rows;
      float ssum = 0.f;
#pragma unroll
      for (int ni = 0; ni < 4; ++ni) {
        const float c = acc[mi][ni][r];
        const float partner = __shfl_xor(c, 1);
        const float s1 = (lane & 1) ? partner : c;
        const float s3 = (lane & 1) ? c : partner;
        const float sp = (s1 / (1.f + __expf(-s1))) * s3;
        const int P = (nt * 256 + wcol + ni * 16 + lrow) >> 1;
        const bool ok = rowok && ((lane & 1) == 0) && (P < 1023);
        if (ok) hbuf[(size_t)(mbase + row) * 1024 + 1 + P] = (bf16)sp;
        ssum += ok ? sp * sp : 0.f;
      }
      ssum += __shfl_xor(ssum, 1);
      ssum += __shfl_xor(ssum, 2);
      ssum += __shfl_xor(ssum, 4);
      ssum += __shfl_xor(ssum, 8);
      if (lrow == 0 && rowok) atomicAdd(ssbuf + mbase + row, ssum);
    }
  }
}

// ---------------- mlp2: BM=256 x BN=256, SPLIT-K x2, dual-buffer plain stores ----------------
// kh=0 writes o_*0, kh=1 writes o_*1 (no atomics, no zero-init; combine sums halves).
// h[:,0] is zero so the MFMA contributes only the space part; combine adds t*W2[:,0].
__global__ __launch_bounds__(1024) void mlp2_kernel(
    const bf16* __restrict__ h_r, const bf16* __restrict__ h_s,
    const bf16* __restrict__ w2b, const bf16* __restrict__ ws2b,
    const int4* __restrict__ wl, const int* __restrict__ wl_n,
    float* __restrict__ o_r0, float* __restrict__ o_r1,
    float* __restrict__ o_s0, float* __restrict__ o_s1)
{
  const int bid = blockIdx.x;
  const int slot = bid % SMAX;
  const int rest = bid / SMAX;        // 0..7
  const int nt = rest & 3, kh = rest >> 2;
  if (slot >= *wl_n) return;
  const int4 wle = wl[slot];
  const int mbase = wle.x, rows = wle.y, eid = wle.z;
  const int tid = threadIdx.x;
  const bool routed = (eid < NE);
  const bf16* abuf = routed ? h_r : h_s;
  const bf16* bmat = routed ? w2b + (size_t)eid * 1023 * 1024 : ws2b;
  float* obuf = routed ? (kh ? o_r1 : o_r0) : (kh ? o_s1 : o_s0);
  const int n0 = nt * 256;
  const int kbase = kh * 512;

  extern __shared__ __align__(16) bf16 smem[];
  bf16* const Asb[2] = {smem, smem + 16384};            // 256x64 each
  bf16* const Bsb[2] = {smem + 32768, smem + 49152};    // 256x64 each

  const int wid = tid >> 6, lane = tid & 63;
  const int srow = lane >> 3;
  const int kbg  = (lane & 7) ^ (srow & 7);
  const bf16 *aG0, *aG1, *bG0, *bG1;
  int aL0o, aL1o, bL0o, bL1o;
  {
    const int r0 = wid * 16;
    int ra0 = r0 + 0 + srow; if (ra0 >= rows) ra0 = rows - 1;
    int ra1 = r0 + 8 + srow; if (ra1 >= rows) ra1 = rows - 1;
    aG0 = abuf + (size_t)(mbase + ra0) * 1024 + kbase + kbg * 8;
    aG1 = abuf + (size_t)(mbase + ra1) * 1024 + kbase + kbg * 8;
    aL0o = (r0 + 0) * 64; aL1o = (r0 + 8) * 64;
    int b0 = n0 + r0 + 0 + srow; if (b0 > 1022) b0 = 1022;
    int b1 = n0 + r0 + 8 + srow; if (b1 > 1022) b1 = 1022;
    bG0 = bmat + (size_t)b0 * 1024 + kbase + kbg * 8;
    bG1 = bmat + (size_t)b1 * 1024 + kbase + kbg * 8;
    bL0o = (r0 + 0) * 64; bL1o = (r0 + 8) * 64;
  }

  const int lrow = lane & 15, quad = lane >> 4, sw = lane & 7;
  const int wrow = (wid >> 2) * 64, wcol = (wid & 3) * 64;
  int aoff[4], boff[4], koff[2];
#pragma unroll
  for (int mi = 0; mi < 4; ++mi) aoff[mi] = (wrow + mi * 16 + lrow) * 64;
#pragma unroll
  for (int ni = 0; ni < 4; ++ni) boff[ni] = (wcol + ni * 16 + lrow) * 64;
#pragma unroll
  for (int kk = 0; kk < 2; ++kk) koff[kk] = ((kk * 4 + quad) ^ sw) * 8;

  const floatx4 fz = {0.f, 0.f, 0.f, 0.f};
  floatx4 acc[4][4];
#pragma unroll
  for (int mi = 0; mi < 4; ++mi)
#pragma unroll
    for (int ni = 0; ni < 4; ++ni) acc[mi][ni] = fz;

#define STAGE2(KE, BUF) { \
    load_lds16(aG0 + (KE), Asb[BUF] + aL0o); load_lds16(aG1 + (KE), Asb[BUF] + aL1o); \
    load_lds16(bG0 + (KE), Bsb[BUF] + bL0o); load_lds16(bG1 + (KE), Bsb[BUF] + bL1o); }

#define COMP2(BUF) { \
_Pragma("unroll") \
    for (int kk = 0; kk < 2; ++kk) { \
      bf16x8 av[4], bv[4]; \
_Pragma("unroll") \
      for (int mi = 0; mi < 4; ++mi) av[mi] = *(const bf16x8*)(Asb[BUF] + aoff[mi] + koff[kk]); \
_Pragma("unroll") \
      for (int ni = 0; ni < 4; ++ni) bv[ni] = *(const bf16x8*)(Bsb[BUF] + boff[ni] + koff[kk]); \
_Pragma("unroll") \
      for (int mi = 0; mi < 4; ++mi) \
_Pragma("unroll") \
        for (int ni = 0; ni < 4; ++ni) \
          acc[mi][ni] = MFMA16(av[mi], bv[ni], acc[mi][ni]); \
    } }

  // 8 K-steps (this block's half of K)
  STAGE2(0, 0)
  STAGE2(64, 1)
#pragma unroll 1
  for (int t = 0; t < 3; ++t) {
    const int ke = t * 128;
    WBAR(4); COMP2(0) BARO; STAGE2(ke + 128, 0)
    WBAR(4); COMP2(1) BARO; STAGE2(ke + 192, 1)
  }
  WBAR(4); COMP2(0)
  WBAR(0); COMP2(1)
#undef STAGE2
#undef COMP2

  // epilogue: plain fp32 stores into this kh's buffer
#pragma unroll
  for (int mi = 0; mi < 4; ++mi) {
#pragma unroll
    for (int r = 0; r < 4; ++r) {
      const int row = wrow + mi * 16 + quad * 4 + r;
      if (row < rows) {
        float* orow = obuf + (size_t)(mbase + row) * 1024;
#pragma unroll
        for (int ni = 0; ni < 4; ++ni) {
          const int n = n0 + wcol + ni * 16 + lrow;
          if (n < 1023) orow[n] = acc[mi][ni][r];
        }
      }
    }
  }
}

// ---------------- final: sum split-K halves + t*W2col0 + LResNet combine + normalize ----------------
__global__ __launch_bounds__(256) void combine_kernel(
    const float* __restrict__ o_r0, const float* __restrict__ o_r1,
    const float* __restrict__ o_s0, const float* __restrict__ o_s1,
    const float* __restrict__ ss_r, const float* __restrict__ ss_z,
    const float* __restrict__ w2c0_r, const float* __restrict__ w2c0_s,
    const int* __restrict__ eidx, const int* __restrict__ pos_of,
    const float* __restrict__ wgt, float* __restrict__ out)
{
  const int t = blockIdx.x, tid = threadIdx.x;
  const int p = pos_of[t];
  const int e = eidx[t];
  const float w = wgt[t];
  const float tz = sqrtf(ss_z[t] + 1.f);   // shared-expert mid time
  const float tr = sqrtf(ss_r[p] + 1.f);   // routed-expert mid time
  const float4 oz0 = ((const float4*)(o_s0 + (size_t)t * 1024))[tid];
  const float4 oz1 = ((const float4*)(o_s1 + (size_t)t * 1024))[tid];
  const float4 oe0 = ((const float4*)(o_r0 + (size_t)p * 1024))[tid];
  const float4 oe1 = ((const float4*)(o_r1 + (size_t)p * 1024))[tid];
  const float4 c0s = ((const float4*)(w2c0_s))[tid];
  const float4 c0r = ((const float4*)(w2c0_r + (size_t)e * 1024))[tid];
  const bool last = (tid == 255);          // n=1023 is padding
  float ozf0 = oz0.x + oz1.x + tz * c0s.x;
  float ozf1 = oz0.y + oz1.y + tz * c0s.y;
  float ozf2 = oz0.z + oz1.z + tz * c0s.z;
  float ozf3 = last ? 0.f : (oz0.w + oz1.w + tz * c0s.w);
  float oef0 = oe0.x + oe1.x + tr * c0r.x;
  float oef1 = oe0.y + oe1.y + tr * c0r.y;
  float oef2 = oe0.z + oe1.z + tr * c0r.z;
  float oef3 = last ? 0.f : (oe0.w + oe1.w + tr * c0r.w);
  const float tw = 2.f * w;
  const float c0 = ozf0 + tw * oef0;
  const float c1 = ozf1 + tw * oef1;
  const float c2 = ozf2 + tw * oef2;
  const float c3 = ozf3 + tw * oef3;
  float sc = c0 * c0 + c1 * c1 + c2 * c2 + c3 * c3;
  float sz = ozf0 * ozf0 + ozf1 * ozf1 + ozf2 * ozf2 + ozf3 * ozf3;
  float sr = oef0 * oef0 + oef1 * oef1 + oef2 * oef2 + oef3 * oef3;
#pragma unroll
  for (int off = 32; off > 0; off >>= 1) {
    sc += __shfl_down(sc, off);
    sz += __shfl_down(sz, off);
    sr += __shfl_down(sr, off);
  }
  __shared__ float rs[3][4];
  if ((tid & 63) == 0) {
    rs[0][tid >> 6] = sc; rs[1][tid >> 6] = sz; rs[2][tid >> 6] = sr;
  }
  __syncthreads();
  const float space2 = rs[0][0] + rs[0][1] + rs[0][2] + rs[0][3];
  const float ss_oz  = rs[1][0] + rs[1][1] + rs[1][2] + rs[1][3];
  const float ss_or  = rs[2][0] + rs[2][1] + rs[2][2] + rs[2][3];
  const float comb0 = sqrtf(ss_oz + 1.f) + 2.f + 2.f * w * sqrtf(ss_or + 1.f);
  const float li = space2 - comb0 * comb0;
  const float inv = 1.f / sqrtf(fmaxf(fabsf(li), 1e-8f));
  float* orow = out + (size_t)t * 1024;
  const int j = 1 + tid * 4;
  orow[j]     = c0 * inv;
  orow[j + 1] = c1 * inv;
  orow[j + 2] = c2 * inv;
  if (!last) orow[j + 3] = c3 * inv;
  if (tid == 0) orow[0] = comb0 * inv;
}

extern "C" void kernel_launch(void* const* d_in, const int* in_sizes, int n_in,
                              void* d_out, int out_size, void* d_ws, size_t ws_size,
                              hipStream_t stream) {
  const float* x      = (const float*)d_in[0];
  const float* gate_w = (const float*)d_in[1];
  const float* gate_b = (const float*)d_in[2];
  const float* W1     = (const float*)d_in[3];
  const float* W3     = (const float*)d_in[4];
  const float* W2     = (const float*)d_in[5];
  const float* Ws1    = (const float*)d_in[6];
  const float* Ws3    = (const float*)d_in[7];
  const float* Ws2    = (const float*)d_in[8];
  float* out = (float*)d_out;

  char* ws = (char*)d_ws;
  size_t off = 0;
  auto alloc = [&](size_t bytes) {
    void* p = ws + off;
    off += (bytes + 255) & ~(size_t)255;
    return p;
  };
  bf16*  x_bf = (bf16*) alloc((size_t)TOK * 1024 * 2);
  bf16*  h_r  = (bf16*) alloc((size_t)TOK * 1024 * 2);
  bf16*  h_s  = (bf16*) alloc((size_t)TOK * 1024 * 2);
  float* o_r0 = (float*)alloc((size_t)TOK * 1024 * 4);
  float* o_s0 = (float*)alloc((size_t)TOK * 1024 * 4);
  float* ss   = (float*)alloc((size_t)2 * TOK * 4);
  int*   eidx = (int*)  alloc((size_t)TOK * 4);
  float* ewgt = (float*)alloc((size_t)TOK * 4);
  int*   perm = (int*)  alloc((size_t)TOK * 4);
  int*   posf = (int*)  alloc((size_t)TOK * 4);
  int4*  wl1  = (int4*) alloc((size_t)SMAX * 16);
  int*   wn   = (int*)  alloc(32);
  float* w2c0_r = (float*)alloc((size_t)NE * 1024 * 4);   // padded [E][1024]
  float* w2c0_s = (float*)alloc((size_t)1024 * 4);
  bf16*  w13  = (bf16*) alloc((size_t)8 * 2046 * 1024 * 2);
  bf16*  ws13 = (bf16*) alloc((size_t)2046 * 1024 * 2);
  bf16*  w2b  = (bf16*) alloc((size_t)8 * 1023 * 1024 * 2);
  bf16*  ws2b = (bf16*) alloc((size_t)1023 * 1024 * 2);

  // split-K second-half buffers ALIAS the w13 region (w13 is dead after mlp1;
  // mlp2's writes are stream-ordered after mlp1 completes; next iteration's prep
  // rewrites w13 only after this iteration's combine consumed o_*1).
  float* o_r1 = (float*)w13;
  float* o_s1 = (float*)w13 + (size_t)TOK * 1024;

  float* ss_r  = ss;
  float* ss_z  = ss + TOK;

  // both MLP kernels use 128KB dynamic LDS (dbuf 256x64 A + 256x64 B)
  const int MLP_LDS = 2 * (256 * 64 + 256 * 64) * 2;  // 131072 B
  (void)hipFuncSetAttribute((const void*)mlp1_kernel,
                            hipFuncAttributeMaxDynamicSharedMemorySize, MLP_LDS);
  (void)hipFuncSetAttribute((const void*)mlp2_kernel,
                            hipFuncAttributeMaxDynamicSharedMemorySize, MLP_LDS);

  prep_kernel<<<GATEB + NCVT, 256, 0, stream>>>(
      x, gate_w, gate_b, W1, W3, W2, Ws1, Ws3, Ws2,
      x_bf, eidx, ewgt, ss, w13, ws13, w2b, ws2b, w2c0_r, w2c0_s, h_r, h_s);
  route_kernel<<<1, 256, 0, stream>>>(eidx, perm, posf, wl1, wn);
  mlp1_kernel<<<8 * SMAX, 1024, MLP_LDS, stream>>>(x_bf, w13, ws13, perm, wl1, wn,
                                                   h_r, h_s, ss_r, ss_z);
  mlp2_kernel<<<8 * SMAX, 1024, MLP_LDS, stream>>>(h_r, h_s, w2b, ws2b, wl1, wn,
                                                   o_r0, o_r1, o_s0, o_s1);
  combine_kernel<<<TOK, 256, 0, stream>>>(o_r0, o_r1, o_s0, o_s1, ss_r, ss_z,
                                          w2c0_r, w2c0_s, eidx, posf, ewgt, out);
}